// Round 6
// baseline (623.918 us; speedup 1.0000x reference)
//
#include <hip/hip_runtime.h>
#include <cmath>

// Problem constants
#define BB 64
#define RR 4608
#define CC 32
#define INN 8
#define OUTT 16

constexpr int RCB    = 24;              // r rows per block
constexpr int NCHUNK = RR / RCB;        // 192
constexpr int NCQ    = CC / 2;          // 16 c-pairs (one wave each)
constexpr int NG     = 8;               // stage-1 reducer groups
constexpr int CPG    = NCHUNK / NG;     // 24 chunks per group

// Flash-style routing pass. One wave per block (no barriers, no LDS).
// lane = (chh in {0,1}) * 32 + bs;  wave covers c-pair {c0,c0+1} x all 64 b.
// Each lane handles 2 b's (bs, bs+32) for its one c.
// W is read global->VGPR via group-broadcast float4 loads (32 lanes of a c
// share each address -> 1 line per group, L1/L2-serviced, zero LDS).
__global__ __launch_bounds__(64, 3)
void caps_pass(const float* __restrict__ x, const float* __restrict__ W,
               const float* __restrict__ V, float* __restrict__ pz,
               float* __restrict__ ps)
{
    const int lane = threadIdx.x;        // 0..63
    const int chh  = lane >> 5;          // which c of the pair
    const int bs   = lane & 31;          // b sub-index
    const int cq   = blockIdx.x;         // 0..15 (c-pair)
    const int ch   = blockIdx.y;         // 0..191 (r-chunk)
    const int c    = cq * 2 + chh;
    const int r0   = ch * RCB;

    // cumulative V for (b=bs, c) and (b=bs+32, c)
    float Vr0[OUTT], Vr1[OUTT];
    {
        const float* vp0 = V + ((size_t)c * BB + bs) * OUTT;
        const float* vp1 = V + ((size_t)c * BB + bs + 32) * OUTT;
#pragma unroll
        for (int q = 0; q < 4; ++q) {
            float4 a = *reinterpret_cast<const float4*>(vp0 + 4 * q);
            float4 b = *reinterpret_cast<const float4*>(vp1 + 4 * q);
            Vr0[4*q]=a.x; Vr0[4*q+1]=a.y; Vr0[4*q+2]=a.z; Vr0[4*q+3]=a.w;
            Vr1[4*q]=b.x; Vr1[4*q+1]=b.y; Vr1[4*q+2]=b.z; Vr1[4*q+3]=b.w;
        }
    }

    float z0 = 0.f, z1 = 0.f;
    float s0[OUTT], s1[OUTT];
#pragma unroll
    for (int o = 0; o < OUTT; ++o) { s0[o] = 0.f; s1[o] = 0.f; }

    // Per-lane W base (depends on c -> 32-dup broadcast addresses).
    const float* Wp  = W + ((size_t)r0 * CC + c) * (INN * OUTT);
    const float* xp0 = x + ((size_t)bs * RR + r0) * INN;
    const float* xp1 = x + ((size_t)(bs + 32) * RR + r0) * INN;

    for (int r = 0; r < RCB; ++r) {
        // x fragments for this r (per-lane distinct, L1/L2-hot: 2 KB slice
        // shared by the 16 consecutive cq-blocks at this r)
        float4 xa0 = *reinterpret_cast<const float4*>(xp0 + r * INN);
        float4 xb0 = *reinterpret_cast<const float4*>(xp0 + r * INN + 4);
        float4 xa1 = *reinterpret_cast<const float4*>(xp1 + r * INN);
        float4 xb1 = *reinterpret_cast<const float4*>(xp1 + r * INN + 4);
        const float x0v[INN] = {xa0.x,xa0.y,xa0.z,xa0.w, xb0.x,xb0.y,xb0.z,xb0.w};
        const float x1v[INN] = {xa1.x,xa1.y,xa1.z,xa1.w, xb1.x,xb1.y,xb1.z,xb1.w};

        float uh0[OUTT], uh1[OUTT];
#pragma unroll
        for (int o = 0; o < OUTT; ++o) { uh0[o] = 0.f; uh1[o] = 0.f; }

        const float4* W4 = reinterpret_cast<const float4*>(Wp);
        // 32 broadcast float4 loads, all imm-offset from one base.
#pragma unroll
        for (int i = 0; i < INN; ++i) {
            const float xi0 = x0v[i];
            const float xi1 = x1v[i];
#pragma unroll
            for (int q = 0; q < 4; ++q) {
                const float4 w = W4[i * 4 + q];
                uh0[q*4+0] = fmaf(xi0, w.x, uh0[q*4+0]);
                uh0[q*4+1] = fmaf(xi0, w.y, uh0[q*4+1]);
                uh0[q*4+2] = fmaf(xi0, w.z, uh0[q*4+2]);
                uh0[q*4+3] = fmaf(xi0, w.w, uh0[q*4+3]);
                uh1[q*4+0] = fmaf(xi1, w.x, uh1[q*4+0]);
                uh1[q*4+1] = fmaf(xi1, w.y, uh1[q*4+1]);
                uh1[q*4+2] = fmaf(xi1, w.z, uh1[q*4+2]);
                uh1[q*4+3] = fmaf(xi1, w.w, uh1[q*4+3]);
            }
        }

        // logits (4-way trees)
        float a0=0.f,a1=0.f,a2=0.f,a3=0.f, b0=0.f,b1=0.f,b2=0.f,b3=0.f;
#pragma unroll
        for (int q = 0; q < 4; ++q) {
            a0 = fmaf(uh0[q],      Vr0[q],      a0);
            a1 = fmaf(uh0[4 + q],  Vr0[4 + q],  a1);
            a2 = fmaf(uh0[8 + q],  Vr0[8 + q],  a2);
            a3 = fmaf(uh0[12 + q], Vr0[12 + q], a3);
            b0 = fmaf(uh1[q],      Vr1[q],      b0);
            b1 = fmaf(uh1[4 + q],  Vr1[4 + q],  b1);
            b2 = fmaf(uh1[8 + q],  Vr1[8 + q],  b2);
            b3 = fmaf(uh1[12 + q], Vr1[12 + q], b3);
        }
        const float p0 = __expf((a0 + a1) + (a2 + a3));  // V=0 iter0 -> uniform
        const float p1 = __expf((b0 + b1) + (b2 + b3));
        z0 += p0;
        z1 += p1;
#pragma unroll
        for (int o = 0; o < OUTT; ++o) {
            s0[o] = fmaf(p0, uh0[o], s0[o]);
            s1[o] = fmaf(p1, uh1[o], s1[o]);
        }

        Wp += CC * INN * OUTT;               // next r (same c): +4096 floats
    }

    // write partials: layout [ch][c][b][o]
    const size_t bc0 = ((size_t)ch * CC + c) * BB + bs;
    const size_t bc1 = bc0 + 32;
    pz[bc0] = z0;
    pz[bc1] = z1;
    float* p0p = ps + bc0 * OUTT;
    float* p1p = ps + bc1 * OUTT;
#pragma unroll
    for (int q = 0; q < 4; ++q) {
        *reinterpret_cast<float4*>(p0p + 4*q) =
            make_float4(s0[4*q], s0[4*q+1], s0[4*q+2], s0[4*q+3]);
        *reinterpret_cast<float4*>(p1p + 4*q) =
            make_float4(s1[4*q], s1[4*q+1], s1[4*q+2], s1[4*q+3]);
    }
}

// Stage-1 reduce: 8 groups x 24 chunks -> mid partials. High parallelism
// (1024 blocks) so the reduction is BW-bound, not latency-bound.
__global__ __launch_bounds__(256)
void caps_reduce1(const float* __restrict__ pz, const float* __restrict__ ps,
                  float* __restrict__ mz, float* __restrict__ ms)
{
    const int g    = blockIdx.y;                        // 0..7
    const int flat = blockIdx.x * 256 + threadIdx.x;    // 0..32767
    const int o    = flat & 15;
    const int bc   = flat >> 4;                         // c*64+b
    const int b    = bc & 63;
    const int c    = bc >> 6;

    float sv = 0.f;
#pragma unroll 4
    for (int j = 0; j < CPG; ++j) {
        const size_t chk = (size_t)g * CPG + j;
        sv += ps[(((chk * CC + c) * BB + b) << 4) + o];
    }
    // z: split this (b,c)'s 24 chunks across the 16 o-threads, then reduce
    float zv = 0.f;
    for (int j = o; j < CPG; j += 16) {
        const size_t chk = (size_t)g * CPG + j;
        zv += pz[(chk * CC + c) * BB + b];
    }
#pragma unroll
    for (int m = 1; m < 16; m <<= 1) zv += __shfl_xor(zv, m);

    ms[(size_t)g * 32768 + flat] = sv;
    if (o == 0) mz[(size_t)g * 2048 + bc] = zv;
}

// Stage-2: final sum over 8 groups, squash, accumulate V or emit output.
template <int LAST>
__global__ __launch_bounds__(256)
void caps_finish(const float* __restrict__ mz, const float* __restrict__ ms,
                 float* __restrict__ V, float* __restrict__ out)
{
    const int flat = blockIdx.x * 256 + threadIdx.x;    // 0..32767
    const int o    = flat & 15;
    const int bc   = flat >> 4;
    const int b    = bc & 63;
    const int c    = bc >> 6;

    float sv = 0.f, zv = 0.f;
#pragma unroll
    for (int g = 0; g < NG; ++g) {
        sv += ms[(size_t)g * 32768 + flat];
        zv += mz[(size_t)g * 2048 + bc];
    }
    const float st = sv / zv;            // s[b,c,o]

    float sq = st * st;
#pragma unroll
    for (int m = 1; m < 16; m <<= 1) sq += __shfl_xor(sq, m);
    const float scale = (sq / (1.0f + sq)) / sqrtf(sq + 1e-8f);
    const float v = st * scale;

    if (LAST) out[((size_t)b * CC + c) * OUTT + o] = v;  // (B,C,OUT)
    else      V[flat] += v;              // V layout [c][b][o] == flat
}

extern "C" void kernel_launch(void* const* d_in, const int* in_sizes, int n_in,
                              void* d_out, int out_size, void* d_ws, size_t ws_size,
                              hipStream_t stream)
{
    const float* x = (const float*)d_in[0];   // (B,R,IN)
    const float* W = (const float*)d_in[1];   // (R,C,IN,OUT)
    float* out = (float*)d_out;               // (B,C,OUT)

    float* wsf = (float*)d_ws;
    float* V  = wsf;                                    // 32768
    float* pz = V  + (size_t)BB * CC * OUTT;            // 393216
    float* ps = pz + (size_t)NCHUNK * CC * BB;          // 6291456
    float* mz = ps + (size_t)NCHUNK * CC * BB * OUTT;   // 16384
    float* ms = mz + (size_t)NG * CC * BB;              // 262144

    hipMemsetAsync(V, 0, (size_t)BB * CC * OUTT * sizeof(float), stream);

    const dim3 pgrid(NCQ, NCHUNK);       // consecutive blocks share r-chunk
    const dim3 rgrid(128, NG);
    for (int it = 0; it < 3; ++it) {
        caps_pass<<<pgrid, 64, 0, stream>>>(x, W, V, pz, ps);
        caps_reduce1<<<rgrid, 256, 0, stream>>>(pz, ps, mz, ms);
        if (it < 2)
            caps_finish<0><<<128, 256, 0, stream>>>(mz, ms, V, out);
        else
            caps_finish<1><<<128, 256, 0, stream>>>(mz, ms, V, out);
    }
}